// Round 4
// baseline (283.657 us; speedup 1.0000x reference)
//
#include <hip/hip_runtime.h>

#define DIM 192
#define PLANE (DIM * DIM)              // 36864
#define VOL ((size_t)PLANE * DIM)      // 7077888
#define NBLK 384                       // 48 j-tiles * 4 i-chunks * 2 batches

__device__ __forceinline__ float robustf(float x) {
    float ax = fabsf(x);
    return (ax <= 0.01f) ? (0.5f * x * x) : (0.01f * (ax - 0.005f));
}

__device__ __forceinline__ float4 ldg4(const float* __restrict__ p) {
    return *(const float4*)p;
}

__device__ __forceinline__ float4 sub_scale(float4 a, float4 b, float s) {
    return make_float4((a.x - b.x) * s, (a.y - b.y) * s,
                       (a.z - b.z) * s, (a.w - b.w) * s);
}

__device__ __forceinline__ float voxel_loss(
    float du_dx, float du_dy, float du_dz,
    float dv_dx, float dv_dy, float dv_dz,
    float dw_dx, float dw_dy, float dw_dz) {
    const float E_xy = 0.5f * (du_dy + dv_dx);
    const float E_xz = 0.5f * (du_dz + dw_dx);
    const float E_yz = 0.5f * (dv_dz + dw_dy);
    const float tr   = du_dx + dv_dy + dw_dz;

    const float rtr = robustf(tr);
    const float rxx = robustf(du_dx), ryy = robustf(dv_dy), rzz = robustf(dw_dz);
    const float rxy = robustf(E_xy),  rxz = robustf(E_xz),  ryz = robustf(E_yz);

    const float energy = 0.5f * rtr * rtr
                       + 0.5f * (rxx * rxx + ryy * ryy + rzz * rzz
                                 + 2.0f * (rxy * rxy + rxz * rxz + ryz * ryz));

    // Replicate the reference expression EXACTLY (not the true determinant).
    const float jac =
          (1.0f + du_dx) * ((1.0f + dv_dy) * (1.0f + dw_dz) - dv_dz * dw_dy)
        - du_dy * (dv_dx * (1.0f + dw_dz) - dv_dz * (1.0f + dw_dx))
        + du_dz * (dv_dx * dw_dy - (1.0f + dv_dy) * (1.0f + dw_dx));

    return energy + 0.1f * fmaxf(-jac, 0.0f);
}

__device__ __forceinline__ float4 zgrad(float4 c, float lf, float rt,
                                        bool leftEdge, bool rightEdge) {
    float4 g;
    g.x = leftEdge  ? (c.y - c.x) : 0.5f * (c.y - lf);
    g.y = 0.5f * (c.z - c.x);
    g.z = 0.5f * (c.w - c.y);
    g.w = rightEdge ? (c.w - c.z) : 0.5f * (rt - c.z);
    return g;
}

// i-march with register rotation; i-chunk depth 48 (minimizes cross-chunk
// boundary-plane refetch: 50/48 amplification). Per-block partial sum is a
// plain store into d_ws (no memset/atomics needed).
__global__ __launch_bounds__(256, 4)
void elastic_main(const float* __restrict__ df, double* __restrict__ partial) {
    const int tx = threadIdx.x;        // 0..63; lanes 0..47 active (float4 over k)
    const int ty = threadIdx.y;        // 0..3 -> j row within block
    const int k4 = tx * 4;
    const int j  = blockIdx.x * 4 + ty;
    const int i0 = blockIdx.y * 48;
    const int b  = blockIdx.z;

    const float* __restrict__ u = df + (size_t)(b * 3 + 0) * VOL;
    const float* __restrict__ v = df + (size_t)(b * 3 + 1) * VOL;
    const float* __restrict__ w = df + (size_t)(b * 3 + 2) * VOL;

    const int jp = (j < DIM - 1) ? j + 1 : j;
    const int jm = (j > 0) ? j - 1 : j;
    const float sy = ((jp - jm) == 2) ? 0.5f : 1.0f;

    const bool act = (tx < 48);
    const bool leftEdge  = (tx == 0);
    const bool rightEdge = (tx == 47);

    float4 um, vm, wm, uc, vc, wc;
    um = vm = wm = uc = vc = wc = make_float4(0.f, 0.f, 0.f, 0.f);

    {
        const int im1 = (i0 > 0) ? i0 - 1 : 0;
        const size_t oM = (size_t)im1 * PLANE + (size_t)j * DIM + k4;
        const size_t oC = (size_t)i0  * PLANE + (size_t)j * DIM + k4;
        if (act) {
            um = ldg4(u + oM); vm = ldg4(v + oM); wm = ldg4(w + oM);
            uc = ldg4(u + oC); vc = ldg4(v + oC); wc = ldg4(w + oC);
        }
    }

    float vsum = 0.0f;

    for (int ii = 0; ii < 48; ++ii) {
        const int i   = i0 + ii;
        const int ip1 = (i < DIM - 1) ? i + 1 : i;
        const int im1 = (i > 0) ? i - 1 : i;
        const float sx = ((ip1 - im1) == 2) ? 0.5f : 1.0f;

        const size_t oP  = (size_t)ip1 * PLANE + (size_t)j  * DIM + k4;
        const size_t oYp = (size_t)i   * PLANE + (size_t)jp * DIM + k4;
        const size_t oYm = (size_t)i   * PLANE + (size_t)jm * DIM + k4;

        float4 up, vp, wp, uyp, uym, vyp, vym, wyp, wym;
        up = vp = wp = make_float4(0.f, 0.f, 0.f, 0.f);
        if (act) {
            up  = ldg4(u + oP);  vp  = ldg4(v + oP);  wp  = ldg4(w + oP);
            uyp = ldg4(u + oYp); uym = ldg4(u + oYm);
            vyp = ldg4(v + oYp); vym = ldg4(v + oYm);
            wyp = ldg4(w + oYp); wym = ldg4(w + oYm);
        }

        const float ulf = __shfl_up(uc.w, 1);
        const float vlf = __shfl_up(vc.w, 1);
        const float wlf = __shfl_up(wc.w, 1);
        const float urt = __shfl_down(uc.x, 1);
        const float vrt = __shfl_down(vc.x, 1);
        const float wrt = __shfl_down(wc.x, 1);

        if (act) {
            const float4 du_dz = zgrad(uc, ulf, urt, leftEdge, rightEdge);
            const float4 dv_dz = zgrad(vc, vlf, vrt, leftEdge, rightEdge);
            const float4 dw_dz = zgrad(wc, wlf, wrt, leftEdge, rightEdge);

            const float4 du_dx = sub_scale(up, um, sx);
            const float4 dv_dx = sub_scale(vp, vm, sx);
            const float4 dw_dx = sub_scale(wp, wm, sx);
            const float4 du_dy = sub_scale(uyp, uym, sy);
            const float4 dv_dy = sub_scale(vyp, vym, sy);
            const float4 dw_dy = sub_scale(wyp, wym, sy);

            vsum += voxel_loss(du_dx.x, du_dy.x, du_dz.x,
                               dv_dx.x, dv_dy.x, dv_dz.x,
                               dw_dx.x, dw_dy.x, dw_dz.x);
            vsum += voxel_loss(du_dx.y, du_dy.y, du_dz.y,
                               dv_dx.y, dv_dy.y, dv_dz.y,
                               dw_dx.y, dw_dy.y, dw_dz.y);
            vsum += voxel_loss(du_dx.z, du_dy.z, du_dz.z,
                               dv_dx.z, dv_dy.z, dv_dz.z,
                               dw_dx.z, dw_dy.z, dw_dz.z);
            vsum += voxel_loss(du_dx.w, du_dy.w, du_dz.w,
                               dv_dx.w, dv_dy.w, dv_dz.w,
                               dw_dx.w, dw_dy.w, dw_dz.w);
        }

        um = uc; vm = vc; wm = wc;
        uc = up; vc = vp; wc = wp;
    }

    #pragma unroll
    for (int off = 32; off > 0; off >>= 1)
        vsum += __shfl_down(vsum, off, 64);

    __shared__ float wpart[4];
    if (tx == 0) wpart[ty] = vsum;
    __syncthreads();
    if (tx == 0 && ty == 0) {
        const int blk = blockIdx.x + 48 * (blockIdx.y + 4 * blockIdx.z);
        partial[blk] = (double)wpart[0] + (double)wpart[1]
                     + (double)wpart[2] + (double)wpart[3];
    }
}

__global__ __launch_bounds__(256)
void elastic_finalize(const double* __restrict__ partial, float* __restrict__ out) {
    const int t = threadIdx.x;
    double s = partial[t] + ((t < NBLK - 256) ? partial[t + 256] : 0.0);

    // wave reduce (f64)
    #pragma unroll
    for (int off = 32; off > 0; off >>= 1)
        s += __shfl_down(s, off, 64);

    __shared__ double wpart[4];
    if ((t & 63) == 0) wpart[t >> 6] = s;
    __syncthreads();
    if (t == 0) {
        double tot = wpart[0] + wpart[1] + wpart[2] + wpart[3];
        out[0] = (float)(tot * (1.0 / 14155776.0));
    }
}

extern "C" void kernel_launch(void* const* d_in, const int* in_sizes, int n_in,
                              void* d_out, int out_size, void* d_ws, size_t ws_size,
                              hipStream_t stream) {
    const float* df = (const float*)d_in[0];
    double* partial = (double*)d_ws;   // NBLK doubles; plain stores, no init needed
    float* out = (float*)d_out;

    dim3 grid(48, 4, 2);       // 48 j-tiles, 4 i-chunks of 48, 2 batches = 384 blocks
    dim3 block(64, 4);
    elastic_main<<<grid, block, 0, stream>>>(df, partial);
    elastic_finalize<<<1, 256, 0, stream>>>(partial, out);
}

// Round 5
// 247.618 us; speedup vs baseline: 1.1455x; 1.1455x over previous
//
#include <hip/hip_runtime.h>

#define DIM 192
#define PLANE (DIM * DIM)              // 36864 floats per x-plane
#define VOL (PLANE * DIM)              // 7077888 floats per field (fits int)
#define DCH 12                         // i-chunk depth
#define NCH (DIM / DCH)                // 16 chunks
#define GT 36                          // g-tiles per plane: 9216 float4 / 256
#define NBLK (GT * NCH * 2)            // 1152 blocks

__device__ __forceinline__ float robustf(float x) {
    // branchless Huber: r = m*(|x| - 0.5*m), m = min(|x|, delta); delta = 0.01
    float ax = fabsf(x);
    float m = fminf(ax, 0.01f);
    return m * (ax - 0.5f * m);
}

__device__ __forceinline__ float4 ldg4(const float* __restrict__ p, int off) {
    return *(const float4*)(p + off);
}

__device__ __forceinline__ float4 sub_scale(float4 a, float4 b, float s) {
    return make_float4((a.x - b.x) * s, (a.y - b.y) * s,
                       (a.z - b.z) * s, (a.w - b.w) * s);
}

__device__ __forceinline__ float voxel_loss(
    float du_dx, float du_dy, float du_dz,
    float dv_dx, float dv_dy, float dv_dz,
    float dw_dx, float dw_dy, float dw_dz) {
    const float E_xy = 0.5f * (du_dy + dv_dx);
    const float E_xz = 0.5f * (du_dz + dw_dx);
    const float E_yz = 0.5f * (dv_dz + dw_dy);
    const float tr   = du_dx + dv_dy + dw_dz;

    const float rtr = robustf(tr);
    const float rxx = robustf(du_dx), ryy = robustf(dv_dy), rzz = robustf(dw_dz);
    const float rxy = robustf(E_xy),  rxz = robustf(E_xz),  ryz = robustf(E_yz);

    const float energy = 0.5f * rtr * rtr
                       + 0.5f * (rxx * rxx + ryy * ryy + rzz * rzz
                                 + 2.0f * (rxy * rxy + rxz * rxz + ryz * ryz));

    // Replicate the reference expression EXACTLY (not the true determinant).
    const float jac =
          (1.0f + du_dx) * ((1.0f + dv_dy) * (1.0f + dw_dz) - dv_dz * dw_dy)
        - du_dy * (dv_dx * (1.0f + dw_dz) - dv_dz * (1.0f + dw_dx))
        + du_dz * (dv_dx * dw_dy - (1.0f + dv_dy) * (1.0f + dw_dx));

    return energy + 0.1f * fmaxf(-jac, 0.0f);
}

__device__ __forceinline__ float4 zgrad(float4 c, float lf, float rt,
                                        bool leftEdge, bool rightEdge) {
    float4 g;
    g.x = leftEdge  ? (c.y - c.x) : 0.5f * (c.y - lf);
    g.y = 0.5f * (c.z - c.x);
    g.z = 0.5f * (c.w - c.y);
    g.w = rightEdge ? (c.w - c.z) : 0.5f * (rt - c.z);
    return g;
}

// Flattened (j,k) mapping: all 64 lanes carry a float4; row boundaries are
// per-lane (g%48); the cross-wave z-halo comes from a predicated scalar load
// on lanes 0/63. i-march with register rotation (x-planes loaded once/chunk).
__global__ __launch_bounds__(256, 4)
void elastic_main(const float* __restrict__ df, double* __restrict__ partial) {
    const int tid  = threadIdx.x;              // 0..255
    const int lane = tid & 63;
    const int g    = blockIdx.x * 256 + tid;   // float4 index in plane, 0..9215
    const int g4   = g * 4;                    // float offset in plane
    const int gmod = g % 48;                   // float4 index within row
    const int j    = g / 48;
    const int i0   = blockIdx.y * DCH;
    const int b    = blockIdx.z;

    const float* __restrict__ u = df + (size_t)(b * 3 + 0) * VOL;
    const float* __restrict__ v = df + (size_t)(b * 3 + 1) * VOL;
    const float* __restrict__ w = df + (size_t)(b * 3 + 2) * VOL;

    const bool leftEdge  = (gmod == 0);
    const bool rightEdge = (gmod == 47);

    const int jp = (j < DIM - 1) ? j + 1 : j;
    const int jm = (j > 0) ? j - 1 : j;
    const float sy = ((jp - jm) == 2) ? 0.5f : 1.0f;
    const int yOfsP = jp * DIM + gmod * 4;     // float offset within plane
    const int yOfsM = jm * DIM + gmod * 4;

    // z-halo: lane0 needs element g4-1 (its lf), lane63 needs g4+4 (its rt)
    const bool doHalo = (lane == 0) || (lane == 63);
    const int hOfs = (lane == 0) ? (leftEdge ? g4 : g4 - 1)
                                 : (rightEdge ? g4 : g4 + 4);

    // rotation registers: center rows of planes max(i-1,0), i
    float4 um, vm, wm, uc, vc, wc;
    {
        const int im1 = (i0 > 0) ? i0 - 1 : 0;
        um = ldg4(u, im1 * PLANE + g4); vm = ldg4(v, im1 * PLANE + g4);
        wm = ldg4(w, im1 * PLANE + g4);
        uc = ldg4(u, i0 * PLANE + g4);  vc = ldg4(v, i0 * PLANE + g4);
        wc = ldg4(w, i0 * PLANE + g4);
    }

    float vsum = 0.0f;
    int oC = i0 * PLANE;                       // plane-i base (float offset)

    for (int ii = 0; ii < DCH; ++ii) {
        const int i = i0 + ii;
        const int oP = oC + ((i < DIM - 1) ? PLANE : 0);   // clamped i+1 plane
        const float sx = (i > 0 && i < DIM - 1) ? 0.5f : 1.0f;

        const float4 up  = ldg4(u, oP + g4);
        const float4 vp  = ldg4(v, oP + g4);
        const float4 wp  = ldg4(w, oP + g4);
        const float4 uyp = ldg4(u, oC + yOfsP);
        const float4 uym = ldg4(u, oC + yOfsM);
        const float4 vyp = ldg4(v, oC + yOfsP);
        const float4 vym = ldg4(v, oC + yOfsM);
        const float4 wyp = ldg4(w, oC + yOfsP);
        const float4 wym = ldg4(w, oC + yOfsM);

        float hu = 0.f, hv = 0.f, hw = 0.f;
        if (doHalo) {                           // 1 predicated dword load/field
            hu = u[oC + hOfs]; hv = v[oC + hOfs]; hw = w[oC + hOfs];
        }

        float ulf = __shfl_up(uc.w, 1);
        float vlf = __shfl_up(vc.w, 1);
        float wlf = __shfl_up(wc.w, 1);
        float urt = __shfl_down(uc.x, 1);
        float vrt = __shfl_down(vc.x, 1);
        float wrt = __shfl_down(wc.x, 1);
        if (lane == 0)  { ulf = hu; vlf = hv; wlf = hw; }
        if (lane == 63) { urt = hu; vrt = hv; wrt = hw; }

        const float4 du_dz = zgrad(uc, ulf, urt, leftEdge, rightEdge);
        const float4 dv_dz = zgrad(vc, vlf, vrt, leftEdge, rightEdge);
        const float4 dw_dz = zgrad(wc, wlf, wrt, leftEdge, rightEdge);

        const float4 du_dx = sub_scale(up, um, sx);
        const float4 dv_dx = sub_scale(vp, vm, sx);
        const float4 dw_dx = sub_scale(wp, wm, sx);
        const float4 du_dy = sub_scale(uyp, uym, sy);
        const float4 dv_dy = sub_scale(vyp, vym, sy);
        const float4 dw_dy = sub_scale(wyp, wym, sy);

        vsum += voxel_loss(du_dx.x, du_dy.x, du_dz.x,
                           dv_dx.x, dv_dy.x, dv_dz.x,
                           dw_dx.x, dw_dy.x, dw_dz.x);
        vsum += voxel_loss(du_dx.y, du_dy.y, du_dz.y,
                           dv_dx.y, dv_dy.y, dv_dz.y,
                           dw_dx.y, dw_dy.y, dw_dz.y);
        vsum += voxel_loss(du_dx.z, du_dy.z, du_dz.z,
                           dv_dx.z, dv_dy.z, dv_dz.z,
                           dw_dx.z, dw_dy.z, dw_dz.z);
        vsum += voxel_loss(du_dx.w, du_dy.w, du_dz.w,
                           dv_dx.w, dv_dy.w, dv_dz.w,
                           dw_dx.w, dw_dy.w, dw_dz.w);

        um = uc; vm = vc; wm = wc;
        uc = up; vc = vp; wc = wp;
        oC += PLANE;
    }

    #pragma unroll
    for (int off = 32; off > 0; off >>= 1)
        vsum += __shfl_down(vsum, off, 64);

    __shared__ float wpart[4];
    if (lane == 0) wpart[tid >> 6] = vsum;
    __syncthreads();
    if (tid == 0) {
        const int blk = blockIdx.x + GT * (blockIdx.y + NCH * blockIdx.z);
        partial[blk] = (double)wpart[0] + (double)wpart[1]
                     + (double)wpart[2] + (double)wpart[3];
    }
}

__global__ __launch_bounds__(256)
void elastic_finalize(const double* __restrict__ partial, float* __restrict__ out) {
    const int t = threadIdx.x;
    double s = 0.0;
    for (int idx = t; idx < NBLK; idx += 256) s += partial[idx];

    #pragma unroll
    for (int off = 32; off > 0; off >>= 1)
        s += __shfl_down(s, off, 64);

    __shared__ double wpart[4];
    if ((t & 63) == 0) wpart[t >> 6] = s;
    __syncthreads();
    if (t == 0) {
        double tot = wpart[0] + wpart[1] + wpart[2] + wpart[3];
        out[0] = (float)(tot * (1.0 / 14155776.0));
    }
}

extern "C" void kernel_launch(void* const* d_in, const int* in_sizes, int n_in,
                              void* d_out, int out_size, void* d_ws, size_t ws_size,
                              hipStream_t stream) {
    const float* df = (const float*)d_in[0];
    double* partial = (double*)d_ws;   // NBLK doubles, plain stores (no init)
    float* out = (float*)d_out;

    dim3 grid(GT, NCH, 2);             // 1152 blocks = 4.5/CU ≈ 18 waves/CU
    elastic_main<<<grid, 256, 0, stream>>>(df, partial);
    elastic_finalize<<<1, 256, 0, stream>>>(partial, out);
}